// Round 7
// baseline (248.199 us; speedup 1.0000x reference)
//
#include <hip/hip_runtime.h>
#include <hip/hip_bf16.h>
#include <stdint.h>

#define B_ 2
#define T_ 2048
#define E_ 2048
#define H_ 16
#define HKV_ 8
#define DH_ 128
#define WINDOW_ 512

typedef unsigned short ush;
typedef float f32x4 __attribute__((ext_vector_type(4)));
typedef float f32x16 __attribute__((ext_vector_type(16)));
typedef __bf16 bf16x8 __attribute__((ext_vector_type(8)));
typedef uint32_t u32x4 __attribute__((ext_vector_type(4)));

static __device__ __forceinline__ ush f2bf(float f) {
    uint32_t u = __float_as_uint(f);
    uint32_t r = (u + 0x7fffu + ((u >> 16) & 1u)) >> 16;
    return (ush)r;
}
static __device__ __forceinline__ float bf2f(ush h) {
    return __uint_as_float(((uint32_t)h) << 16);
}

// ---------------- fused fp32 -> bf16 cast for all 5 inputs (grid-stride) --------
__global__ __launch_bounds__(256) void cast_all(const float* __restrict__ x,
        const float* __restrict__ wq, const float* __restrict__ wk,
        const float* __restrict__ wv, const float* __restrict__ wo,
        ush* __restrict__ dst) {
    const int stride = gridDim.x * blockDim.x;
    for (int i = blockIdx.x * blockDim.x + threadIdx.x; i < 5242880; i += stride) {
        const float4* src;
        if (i < 2097152)      src = (const float4*)x  + i;
        else if (i < 3145728) src = (const float4*)wq + (i - 2097152);
        else if (i < 3670016) src = (const float4*)wk + (i - 3145728);
        else if (i < 4194304) src = (const float4*)wv + (i - 3670016);
        else                  src = (const float4*)wo + (i - 4194304);
        const float4 f = *src;
        ushort4 o;
        o.x = f2bf(f.x); o.y = f2bf(f.y); o.z = f2bf(f.z); o.w = f2bf(f.w);
        reinterpret_cast<ushort4*>(dst)[i] = o;
    }
}

// ---------------- bf16 GEMM v4: (M_REP*64) x 256 tile, BK=32, 32x32x16 MFMA ------
// 8 waves (2M x 4N), 4 LDS buffers, stage t+3 during t, counted vmcnt (never 0
// until tail). C = A * B^T (A:[M][K], Bm:[N][K]).
// Chunk swizzle: LDS chunk (row, c) holds global chunk (row, c ^ ((row>>1)&3)).
// Safety: read buf t&3; stage at iter t targets (t+3)&3 (disjoint); buf t&3 is
// next written by the stage issued in iter t+1, which is after the end-of-t
// barrier behind which all iter-t reads completed. vmcnt(2L) before barrier
// confirms tile t+1 resident (leaves t+2, t+3 in flight).
// MFMA layouts (guide m74/m101): A,B: row/col = lane&31, k = 8*(lane>>5)+e.
// C/D: col = lane&31, row = (r&3) + 8*(r>>2) + 4*(lane>>5), r in [0,16).
template <int M_REP, int MODE>
__global__ __launch_bounds__(512, 2) void gemm_bt4(
    const ush* __restrict__ A, const ush* __restrict__ Bm,
    float* __restrict__ Cf, ush* __restrict__ q, ush* __restrict__ k, ush* __restrict__ vT,
    int M, int N, int K)
{
    __shared__ ush As[4][M_REP * 64 * 32];   // M_REP=4: 64KB, M_REP=2: 32KB
    __shared__ ush Bs[4][256 * 32];          // 64KB
    const int tid = threadIdx.x;
    const int lane = tid & 63;
    const int wid = tid >> 6;               // 0..7
    const int wr = wid >> 2, wc = wid & 3;  // M-half, N-quarter
    const int l31 = lane & 31, lh = lane >> 5;
    const int gm0 = blockIdx.x * (M_REP * 64), gn0 = blockIdx.y * 256;

    f32x16 acc[M_REP][2] = {};   // per-wave (M_REP*32) x 64 output in 32x32 frags

    auto stage = [&](int kt, int buf) {
#pragma unroll
        for (int i = 0; i < M_REP / 2; ++i) {        // A: M_REP*256 chunks
            const int C = i * 512 + tid;
            const int r = C >> 2, c = C & 3;
            const ush* src = A + (size_t)(gm0 + r) * K + (kt << 5)
                             + ((c ^ ((r >> 1) & 3)) << 3);
            __builtin_amdgcn_global_load_lds(
                (const __attribute__((address_space(1))) void*)src,
                (__attribute__((address_space(3))) void*)(&As[buf][C << 3]), 16, 0, 0);
        }
#pragma unroll
        for (int i = 0; i < 2; ++i) {                // B: 1024 chunks
            const int C = i * 512 + tid;
            const int r = C >> 2, c = C & 3;
            const ush* src = Bm + (size_t)(gn0 + r) * K + (kt << 5)
                             + ((c ^ ((r >> 1) & 3)) << 3);
            __builtin_amdgcn_global_load_lds(
                (const __attribute__((address_space(1))) void*)src,
                (__attribute__((address_space(3))) void*)(&Bs[buf][C << 3]), 16, 0, 0);
        }
    };

    const int nt = K >> 5;   // K/32, >= 4

    // prologue: stage tiles 0,1,2; confirm tile 0 (leave 2 tiles = 2L in flight)
    stage(0, 0); stage(1, 1); stage(2, 2);
    if constexpr (M_REP == 4) asm volatile("s_waitcnt vmcnt(8)" ::: "memory");
    else                      asm volatile("s_waitcnt vmcnt(6)" ::: "memory");
    __builtin_amdgcn_s_barrier();
    __builtin_amdgcn_sched_barrier(0);

    for (int t = 0; t < nt; ++t) {
        const int buf = t & 3;
        bf16x8 af[M_REP][2], bfr[2][2];

        // fragment reads: A row=own 32-row block + l31, k-chunk = ks*2+lh (swizzled)
#pragma unroll
        for (int mf = 0; mf < M_REP; ++mf) {
            const int row = wr * (M_REP * 32) + mf * 32 + l31;
            const int sw = (row >> 1) & 3;
#pragma unroll
            for (int ks = 0; ks < 2; ++ks)
                af[mf][ks] = *reinterpret_cast<const bf16x8*>(
                    &As[buf][row * 32 + (((ks * 2 + lh) ^ sw) << 3)]);
        }
#pragma unroll
        for (int nf = 0; nf < 2; ++nf) {
            const int row = wc * 64 + nf * 32 + l31;
            const int sw = (row >> 1) & 3;
#pragma unroll
            for (int ks = 0; ks < 2; ++ks)
                bfr[nf][ks] = *reinterpret_cast<const bf16x8*>(
                    &Bs[buf][row * 32 + (((ks * 2 + lh) ^ sw) << 3)]);
        }

        if (t + 3 < nt) stage(t + 3, (t + 3) & 3);

        __builtin_amdgcn_s_setprio(1);
#pragma unroll
        for (int ks = 0; ks < 2; ++ks)
#pragma unroll
            for (int mf = 0; mf < M_REP; ++mf)
#pragma unroll
                for (int nf = 0; nf < 2; ++nf)
                    acc[mf][nf] = __builtin_amdgcn_mfma_f32_32x32x16_bf16(
                        af[mf][ks], bfr[nf][ks], acc[mf][nf], 0, 0, 0);
        __builtin_amdgcn_s_setprio(0);

        // counted vmcnt: confirm tile t+1; leave younger stages in flight
        if (t + 3 < nt) {
            if constexpr (M_REP == 4) asm volatile("s_waitcnt vmcnt(8)" ::: "memory");
            else                      asm volatile("s_waitcnt vmcnt(6)" ::: "memory");
        } else if (t + 2 < nt) {
            if constexpr (M_REP == 4) asm volatile("s_waitcnt vmcnt(4)" ::: "memory");
            else                      asm volatile("s_waitcnt vmcnt(3)" ::: "memory");
        } else if (t + 1 < nt) {
            asm volatile("s_waitcnt vmcnt(0)" ::: "memory");
        }
        __builtin_amdgcn_s_barrier();
        __builtin_amdgcn_sched_barrier(0);
    }

    // epilogue: 32x32 C/D layout
#pragma unroll
    for (int mf = 0; mf < M_REP; ++mf) {
        const int rbase = gm0 + wr * (M_REP * 32) + mf * 32 + 4 * lh;
#pragma unroll
        for (int nf = 0; nf < 2; ++nf) {
            const int col = gn0 + wc * 64 + nf * 32 + l31;
#pragma unroll
            for (int r = 0; r < 16; ++r) {
                const int row = rbase + (r & 3) + 8 * (r >> 2);
                const float v = acc[mf][nf][r];
                if (MODE == 1) {
                    Cf[(size_t)row * N + col] = v;
                } else {
                    const int bb = row >> 11, tt = row & (T_ - 1);
                    const ush val = f2bf(v);
                    if (col < H_ * DH_) {
                        const int hh = col >> 7, d = col & 127;
                        q[((((size_t)bb * H_ + hh) * T_ + tt) << 7) + d] = val;
                    } else if (col < H_ * DH_ + HKV_ * DH_) {
                        const int c2 = col - H_ * DH_;
                        const int hh = c2 >> 7, d = c2 & 127;
                        k[((((size_t)bb * HKV_ + hh) * T_ + tt) << 7) + d] = val;
                    } else {
                        const int c2 = col - H_ * DH_ - HKV_ * DH_;
                        const int hh = c2 >> 7, d = c2 & 127;
                        vT[((size_t)((bb * HKV_ + hh) * DH_ + d) << 11) + tt] = val;
                    }
                }
            }
        }
    }
}

// ---------------- per-head RMSNorm + RoPE (+ q scale), in place ----------------
__global__ __launch_bounds__(256) void norm_rope(ush* __restrict__ q, ush* __restrict__ k,
                                                 const float* __restrict__ qw,
                                                 const float* __restrict__ kw)
{
    const int lane = threadIdx.x & 63;
    const int row = blockIdx.x * 4 + (threadIdx.x >> 6);
    const int NQ = B_ * H_ * T_;
    ush* p; const float* w; int t; bool isq = (row < NQ);
    if (isq) { p = q + ((size_t)row << 7); t = row & (T_ - 1); w = qw; }
    else     { int r2 = row - NQ; p = k + ((size_t)r2 << 7); t = r2 & (T_ - 1); w = kw; }

    float x0 = bf2f(p[lane]);
    float x1 = bf2f(p[lane + 64]);
    float ss = x0 * x0 + x1 * x1;
#pragma unroll
    for (int off = 32; off; off >>= 1) ss += __shfl_xor(ss, off);
    const float rms = rsqrtf(ss * (1.0f / 128.0f) + 1e-6f);
    float y0 = x0 * rms * (1.0f + w[lane]);
    float y1 = x1 * rms * (1.0f + w[lane + 64]);

    const float invf = expf(-(float)lane * 0.14391156831212787f);
    const float fr = (float)t * invf;
    const float c = cosf(fr), s = sinf(fr);
    float o0 = y0 * c - y1 * s;
    float o1 = y1 * c + y0 * s;
    if (isq) { o0 *= 0.08838834764831845f; o1 *= 0.08838834764831845f; }
    p[lane] = f2bf(o0);
    p[lane + 64] = f2bf(o1);
}

// ---------------- MFMA flash attention (sliding window), builtin-only ----------------
__global__ __launch_bounds__(256) void attn_mfma(const ush* __restrict__ q,
        const ush* __restrict__ k, const ush* __restrict__ vT, ush* __restrict__ ctx)
{
    __shared__ ush Ks[2][32 * 128];   // [key][d] linear
    __shared__ ush Vs[2][128 * 32];   // [d][key] (V^T tile)
    const int tid = threadIdx.x;
    const int lane = tid & 63;
    const int w = tid >> 6;
    const int g = lane >> 4;
    const int t = lane & 15;

    int bi = blockIdx.x;
    bi = (bi & 7) * 128 + (bi >> 3);
    const int qtile = bi & 31;
    const int hh = (bi >> 5) & 15;
    const int b = bi >> 9;
    const int qb = qtile * 64;
    const int hkv = hh >> 1;

    const ush* qptr = q + ((((size_t)b * H_ + hh) * T_ + qb) << 7);
    const ush* kbase = k + (((size_t)b * HKV_ + hkv) << 18);
    const ush* vtbase = vT + (((size_t)b * HKV_ + hkv) << 18);

    bf16x8 qf[4];
#pragma unroll
    for (int c = 0; c < 4; ++c)
        qf[c] = *reinterpret_cast<const bf16x8*>(qptr + ((16 * w + t) << 7) + 32 * c + 8 * g);

    const int kstart = (qb >= WINDOW_) ? (qb - WINDOW_) : 0;
    const int nt = (qb + 64 - kstart) >> 5;

    auto stage = [&](int ti, int buf) {
        const int kt0 = kstart + (ti << 5);
#pragma unroll
        for (int i = 0; i < 2; ++i) {
            const int C = w * 128 + i * 64 + lane;
            {
                const int row = C >> 4, ch = C & 15;
                const ush* gk = kbase + ((size_t)(kt0 + row) << 7) + ch * 8;
                __builtin_amdgcn_global_load_lds(
                    (const __attribute__((address_space(1))) void*)gk,
                    (__attribute__((address_space(3))) void*)(&Ks[buf][(w * 128 + i * 64) * 8]),
                    16, 0, 0);
            }
            {
                const int row = C >> 2, ch = C & 3;
                const ush* gv = vtbase + ((size_t)row << 11) + kt0 + ch * 8;
                __builtin_amdgcn_global_load_lds(
                    (const __attribute__((address_space(1))) void*)gv,
                    (__attribute__((address_space(3))) void*)(&Vs[buf][(w * 128 + i * 64) * 8]),
                    16, 0, 0);
            }
        }
    };

    float m = -1e30f, lsum = 0.f;
    f32x4 o[8] = {};

    stage(0, 0);
    __syncthreads();

    for (int ti = 0; ti < nt; ++ti) {
        const int cur = ti & 1;
        if (ti + 1 < nt) stage(ti + 1, cur ^ 1);
        const int kt0 = kstart + (ti << 5);
        const int qw0 = qb + 16 * w;
        const bool active = (kt0 + 31 >= qw0 - WINDOW_) && (kt0 <= qw0 + 15);
        if (active) {
            f32x4 st[2] = {};
#pragma unroll
            for (int s = 0; s < 2; ++s)
#pragma unroll
                for (int c = 0; c < 4; ++c) {
                    bf16x8 kf = *reinterpret_cast<const bf16x8*>(
                        &Ks[cur][(16 * s + t) * 128 + 32 * c + 8 * g]);
                    st[s] = __builtin_amdgcn_mfma_f32_16x16x32_bf16(kf, qf[c], st[s], 0, 0, 0);
                }
            const int tg = qb + 16 * w + t;
            float e[2][4];
            float mymax = -3e38f;
#pragma unroll
            for (int s = 0; s < 2; ++s)
#pragma unroll
                for (int r = 0; r < 4; ++r) {
                    const int key = kt0 + 16 * s + 4 * g + r;
                    const int dist = tg - key;
                    const bool valid = (dist >= 0) && (dist <= WINDOW_);
                    const float sv = valid ? st[s][r] : -3e38f;
                    e[s][r] = sv;
                    mymax = fmaxf(mymax, sv);
                }
            mymax = fmaxf(mymax, __shfl_xor(mymax, 16));
            mymax = fmaxf(mymax, __shfl_xor(mymax, 32));
            const float mn = fmaxf(m, mymax);
            const float sc = __expf(m - mn);
            float esum = 0.f;
#pragma unroll
            for (int s = 0; s < 2; ++s)
#pragma unroll
                for (int r = 0; r < 4; ++r) {
                    const float ev = __expf(e[s][r] - mn);
                    e[s][r] = ev;
                    esum += ev;
                }
            esum += __shfl_xor(esum, 16);
            esum += __shfl_xor(esum, 32);
            lsum = lsum * sc + esum;
            m = mn;
#pragma unroll
            for (int ds = 0; ds < 8; ++ds) {
                o[ds][0] *= sc; o[ds][1] *= sc; o[ds][2] *= sc; o[ds][3] *= sc;
            }
            uint32_t word[2][2];
#pragma unroll
            for (int s = 0; s < 2; ++s)
#pragma unroll
                for (int wd = 0; wd < 2; ++wd)
                    word[s][wd] = (uint32_t)f2bf(e[s][2 * wd])
                                | ((uint32_t)f2bf(e[s][2 * wd + 1]) << 16);
            u32x4 bw;
#pragma unroll
            for (int e2 = 0; e2 < 4; ++e2) {
                const int srcl = 16 * (2 * (g & 1) + (e2 >> 1)) + t;
                const uint32_t v0 = __shfl(word[0][e2 & 1], srcl);
                const uint32_t v1 = __shfl(word[1][e2 & 1], srcl);
                bw[e2] = (g >= 2) ? v1 : v0;
            }
            const bf16x8 pF = __builtin_bit_cast(bf16x8, bw);
#pragma unroll
            for (int ds = 0; ds < 8; ++ds) {
                bf16x8 vtF = *reinterpret_cast<const bf16x8*>(
                    &Vs[cur][(16 * ds + t) * 32 + 8 * g]);
                o[ds] = __builtin_amdgcn_mfma_f32_16x16x32_bf16(vtF, pF, o[ds], 0, 0, 0);
            }
        }
        __syncthreads();
    }

    const float linv = 1.0f / lsum;
    ush* cptr = ctx + (((size_t)b * T_ + qb + 16 * w + t) * (H_ * DH_)) + hh * DH_;
#pragma unroll
    for (int ds = 0; ds < 8; ++ds) {
        ushort4 pk;
        pk.x = f2bf(o[ds][0] * linv);
        pk.y = f2bf(o[ds][1] * linv);
        pk.z = f2bf(o[ds][2] * linv);
        pk.w = f2bf(o[ds][3] * linv);
        *reinterpret_cast<ushort4*>(cptr + 16 * ds + 4 * g) = pk;
    }
}

// ---------------- host launcher ----------------
extern "C" void kernel_launch(void* const* d_in, const int* in_sizes, int n_in,
                              void* d_out, int out_size, void* d_ws, size_t ws_size,
                              hipStream_t stream)
{
    const float* x   = (const float*)d_in[0];
    const float* wq  = (const float*)d_in[1];
    const float* wk  = (const float*)d_in[2];
    const float* wv  = (const float*)d_in[3];
    const float* wo  = (const float*)d_in[4];
    const float* qnw = (const float*)d_in[5];
    const float* knw = (const float*)d_in[6];
    float* out = (float*)d_out;

    ush* ws    = (ush*)d_ws;
    ush* xbf   = ws;                      // [4096][2048]
    ush* wqkv  = xbf  + 8388608;          // [4096][2048]
    ush* wobf  = wqkv + 8388608;          // [2048][2048]
    ush* qraw  = wobf + 4194304;          // [B][H][T][DH]
    ush* kraw  = qraw + 8388608;          // [B][HKV][T][DH]
    ush* vTb   = kraw + 4194304;          // [B][HKV][DH][T]
    ush* ctx   = vTb  + 4194304;          // [B][T][H*DH]

    cast_all<<<2048, 256, 0, stream>>>(x, wq, wk, wv, wo, ws);

    // QKV: 256x256 tiles -> 16x16 = 256 blocks (1/CU)
    gemm_bt4<4, 0><<<dim3(16, 16), 512, 0, stream>>>(xbf, wqkv, nullptr, qraw, kraw, vTb,
                                                     4096, 4096, 2048);
    norm_rope<<<(65536 + 32768) / 4, 256, 0, stream>>>(qraw, kraw, qnw, knw);
    attn_mfma<<<1024, 256, 0, stream>>>(qraw, kraw, vTb, ctx);
    // out-proj: 128x256 tiles -> 32x8 = 256 blocks (1/CU)
    gemm_bt4<2, 1><<<dim3(32, 8), 512, 0, stream>>>(ctx, wobf, out, nullptr, nullptr, nullptr,
                                                    4096, 2048, 2048);
    (void)in_sizes; (void)n_in; (void)out_size; (void)ws_size;
}

// Round 8
// 236.049 us; speedup vs baseline: 1.0515x; 1.0515x over previous
//
#include <hip/hip_runtime.h>
#include <hip/hip_bf16.h>
#include <stdint.h>

#define B_ 2
#define T_ 2048
#define E_ 2048
#define H_ 16
#define HKV_ 8
#define DH_ 128
#define WINDOW_ 512

typedef unsigned short ush;
typedef float f32x4 __attribute__((ext_vector_type(4)));
typedef __bf16 bf16x8 __attribute__((ext_vector_type(8)));
typedef uint32_t u32x4 __attribute__((ext_vector_type(4)));

static __device__ __forceinline__ ush f2bf(float f) {
    uint32_t u = __float_as_uint(f);
    uint32_t r = (u + 0x7fffu + ((u >> 16) & 1u)) >> 16;
    return (ush)r;
}
static __device__ __forceinline__ float bf2f(ush h) {
    return __uint_as_float(((uint32_t)h) << 16);
}

// ---------------- fused fp32 -> bf16 cast for all 5 inputs (grid-stride) --------
__global__ __launch_bounds__(256) void cast_all(const float* __restrict__ x,
        const float* __restrict__ wq, const float* __restrict__ wk,
        const float* __restrict__ wv, const float* __restrict__ wo,
        ush* __restrict__ dst) {
    const int stride = gridDim.x * blockDim.x;
    for (int i = blockIdx.x * blockDim.x + threadIdx.x; i < 5242880; i += stride) {
        const float4* src;
        if (i < 2097152)      src = (const float4*)x  + i;
        else if (i < 3145728) src = (const float4*)wq + (i - 2097152);
        else if (i < 3670016) src = (const float4*)wk + (i - 3145728);
        else if (i < 4194304) src = (const float4*)wv + (i - 3670016);
        else                  src = (const float4*)wo + (i - 4194304);
        const float4 f = *src;
        ushort4 o;
        o.x = f2bf(f.x); o.y = f2bf(f.y); o.z = f2bf(f.z); o.w = f2bf(f.w);
        reinterpret_cast<ushort4*>(dst)[i] = o;
    }
}

// ---------------- bf16 GEMM v5: (MF*32) x 256 tile, BK=64, phase-split K-tile ----
// R6-proven addressing (128B LDS rows, chunk=(4ks+g)^(t&7), zero conflicts),
// 16x16x32 MFMA, double-buffer. 8 waves = 2M x 4N; wave owns (MF*16) x 64.
// Per K64-tile: MF/2 phases x {ds_read af[2][2]; (p0: bfr[4][2] + stage t+1);
// barrier; setprio MFMA x16; barrier}. Stages stay in flight across phase
// barriers; single vmcnt(0) at tile end (~3 phases after issue = pre-drained).
// Race-free: a wave's tile-t ds_reads complete before its end-of-tile barrier
// (FIFO lgkmcnt drained by MFMA use), so post-barrier stages into buf^1 are safe.
template <int MF, int MODE>
__global__ __launch_bounds__(512, 2) void gemm_bt5(
    const ush* __restrict__ A, const ush* __restrict__ Bm,
    float* __restrict__ Cf, ush* __restrict__ q, ush* __restrict__ k, ush* __restrict__ vT,
    int M, int N, int K)
{
    constexpr int BM = MF * 32;                 // 256 (QKV) or 128 (out-proj)
    __shared__ ush As[2][BM * 64];              // 64 KiB / 32 KiB
    __shared__ ush Bs[2][256 * 64];             // 64 KiB
    const int tid = threadIdx.x;
    const int lane = tid & 63;
    const int wid = tid >> 6;                   // 0..7
    const int wr = wid >> 2, wc = wid & 3;      // M-half, N-quarter
    const int g = lane >> 4, t = lane & 15;
    const int gm0 = blockIdx.x * BM, gn0 = blockIdx.y * 256;

    f32x4 acc[MF][4] = {};                      // wave: (MF*16) x 64 output

    auto stageA = [&](int kt, int buf) {
#pragma unroll
        for (int i = 0; i < BM / 64; ++i) {     // BM*8 chunks / 512 threads
            const int C = i * 512 + tid;
            const int r = C >> 3, c = C & 7;
            const ush* src = A + (size_t)(gm0 + r) * K + (kt << 6) + ((c ^ (r & 7)) << 3);
            __builtin_amdgcn_global_load_lds(
                (const __attribute__((address_space(1))) void*)src,
                (__attribute__((address_space(3))) void*)(&As[buf][C << 3]), 16, 0, 0);
        }
    };
    auto stageB = [&](int kt, int buf) {
#pragma unroll
        for (int i = 0; i < 4; ++i) {
            const int C = i * 512 + tid;
            const int r = C >> 3, c = C & 7;
            const ush* src = Bm + (size_t)(gn0 + r) * K + (kt << 6) + ((c ^ (r & 7)) << 3);
            __builtin_amdgcn_global_load_lds(
                (const __attribute__((address_space(1))) void*)src,
                (__attribute__((address_space(3))) void*)(&Bs[buf][C << 3]), 16, 0, 0);
        }
    };

    const int nt = K >> 6;   // >= 2

    // prologue: stage tile 0, drain, publish
    stageA(0, 0); stageB(0, 0);
    asm volatile("s_waitcnt vmcnt(0)" ::: "memory");
    __builtin_amdgcn_s_barrier();
    __builtin_amdgcn_sched_barrier(0);

    for (int kt = 0; kt < nt; ++kt) {
        const int cur = kt & 1;
        bf16x8 bfr[4][2];

#pragma unroll
        for (int p = 0; p < MF / 2; ++p) {
            bf16x8 af[2][2];
#pragma unroll
            for (int mm = 0; mm < 2; ++mm)
#pragma unroll
                for (int ks = 0; ks < 2; ++ks) {
                    const int row = wr * (MF * 16) + (2 * p + mm) * 16 + t;
                    af[mm][ks] = *reinterpret_cast<const bf16x8*>(
                        &As[cur][row * 64 + ((((ks << 2) + g) ^ (t & 7)) << 3)]);
                }
            if (p == 0) {
#pragma unroll
                for (int nf = 0; nf < 4; ++nf)
#pragma unroll
                    for (int ks = 0; ks < 2; ++ks) {
                        const int row = wc * 64 + nf * 16 + t;
                        bfr[nf][ks] = *reinterpret_cast<const bf16x8*>(
                            &Bs[cur][row * 64 + ((((ks << 2) + g) ^ (t & 7)) << 3)]);
                    }
                if (kt + 1 < nt) { stageA(kt + 1, cur ^ 1); stageB(kt + 1, cur ^ 1); }
            }
            __builtin_amdgcn_s_barrier();
            __builtin_amdgcn_s_setprio(1);
#pragma unroll
            for (int ks = 0; ks < 2; ++ks)
#pragma unroll
                for (int mm = 0; mm < 2; ++mm)
#pragma unroll
                    for (int nf = 0; nf < 4; ++nf)
                        acc[2 * p + mm][nf] = __builtin_amdgcn_mfma_f32_16x16x32_bf16(
                            af[mm][ks], bfr[nf][ks], acc[2 * p + mm][nf], 0, 0, 0);
            __builtin_amdgcn_s_setprio(0);
            if (p == MF / 2 - 1 && kt + 1 < nt)
                asm volatile("s_waitcnt vmcnt(0)" ::: "memory");
            __builtin_amdgcn_s_barrier();
            __builtin_amdgcn_sched_barrier(0);
        }
    }

    // epilogue: 16x16 C/D layout col=lane&15, row=4*(lane>>4)+r
    const int rsub = (lane >> 4) << 2;
    const int csub = lane & 15;
#pragma unroll
    for (int mf = 0; mf < MF; ++mf) {
        const int row0 = gm0 + wr * (MF * 16) + mf * 16 + rsub;
#pragma unroll
        for (int nf = 0; nf < 4; ++nf) {
            const int col = gn0 + wc * 64 + nf * 16 + csub;
#pragma unroll
            for (int r = 0; r < 4; ++r) {
                const int row = row0 + r;
                if (MODE == 1) {
                    Cf[(size_t)row * N + col] = acc[mf][nf][r];
                } else {
                    const int bb = row >> 11, tt = row & (T_ - 1);
                    const ush val = f2bf(acc[mf][nf][r]);
                    if (col < H_ * DH_) {
                        const int hh = col >> 7, d = col & 127;
                        q[((((size_t)bb * H_ + hh) * T_ + tt) << 7) + d] = val;
                    } else if (col < H_ * DH_ + HKV_ * DH_) {
                        const int c2 = col - H_ * DH_;
                        const int hh = c2 >> 7, d = c2 & 127;
                        k[((((size_t)bb * HKV_ + hh) * T_ + tt) << 7) + d] = val;
                    } else {
                        const int c2 = col - H_ * DH_ - HKV_ * DH_;
                        const int hh = c2 >> 7, d = c2 & 127;
                        vT[((size_t)((bb * HKV_ + hh) * DH_ + d) << 11) + tt] = val;
                    }
                }
            }
        }
    }
}

// ---------------- per-head RMSNorm + RoPE (+ q scale), in place ----------------
__global__ __launch_bounds__(256) void norm_rope(ush* __restrict__ q, ush* __restrict__ k,
                                                 const float* __restrict__ qw,
                                                 const float* __restrict__ kw)
{
    const int lane = threadIdx.x & 63;
    const int row = blockIdx.x * 4 + (threadIdx.x >> 6);
    const int NQ = B_ * H_ * T_;
    ush* p; const float* w; int t; bool isq = (row < NQ);
    if (isq) { p = q + ((size_t)row << 7); t = row & (T_ - 1); w = qw; }
    else     { int r2 = row - NQ; p = k + ((size_t)r2 << 7); t = r2 & (T_ - 1); w = kw; }

    float x0 = bf2f(p[lane]);
    float x1 = bf2f(p[lane + 64]);
    float ss = x0 * x0 + x1 * x1;
#pragma unroll
    for (int off = 32; off; off >>= 1) ss += __shfl_xor(ss, off);
    const float rms = rsqrtf(ss * (1.0f / 128.0f) + 1e-6f);
    float y0 = x0 * rms * (1.0f + w[lane]);
    float y1 = x1 * rms * (1.0f + w[lane + 64]);

    const float invf = expf(-(float)lane * 0.14391156831212787f);
    const float fr = (float)t * invf;
    const float c = cosf(fr), s = sinf(fr);
    float o0 = y0 * c - y1 * s;
    float o1 = y1 * c + y0 * s;
    if (isq) { o0 *= 0.08838834764831845f; o1 *= 0.08838834764831845f; }
    p[lane] = f2bf(o0);
    p[lane + 64] = f2bf(o1);
}

// ---------------- MFMA flash attention (sliding window), builtin-only ----------------
__global__ __launch_bounds__(256) void attn_mfma(const ush* __restrict__ q,
        const ush* __restrict__ k, const ush* __restrict__ vT, ush* __restrict__ ctx)
{
    __shared__ ush Ks[2][32 * 128];   // [key][d] linear
    __shared__ ush Vs[2][128 * 32];   // [d][key] (V^T tile)
    const int tid = threadIdx.x;
    const int lane = tid & 63;
    const int w = tid >> 6;
    const int g = lane >> 4;
    const int t = lane & 15;

    int bi = blockIdx.x;
    bi = (bi & 7) * 128 + (bi >> 3);
    const int qtile = bi & 31;
    const int hh = (bi >> 5) & 15;
    const int b = bi >> 9;
    const int qb = qtile * 64;
    const int hkv = hh >> 1;

    const ush* qptr = q + ((((size_t)b * H_ + hh) * T_ + qb) << 7);
    const ush* kbase = k + (((size_t)b * HKV_ + hkv) << 18);
    const ush* vtbase = vT + (((size_t)b * HKV_ + hkv) << 18);

    bf16x8 qf[4];
#pragma unroll
    for (int c = 0; c < 4; ++c)
        qf[c] = *reinterpret_cast<const bf16x8*>(qptr + ((16 * w + t) << 7) + 32 * c + 8 * g);

    const int kstart = (qb >= WINDOW_) ? (qb - WINDOW_) : 0;
    const int nt = (qb + 64 - kstart) >> 5;

    auto stage = [&](int ti, int buf) {
        const int kt0 = kstart + (ti << 5);
#pragma unroll
        for (int i = 0; i < 2; ++i) {
            const int C = w * 128 + i * 64 + lane;
            {
                const int row = C >> 4, ch = C & 15;
                const ush* gk = kbase + ((size_t)(kt0 + row) << 7) + ch * 8;
                __builtin_amdgcn_global_load_lds(
                    (const __attribute__((address_space(1))) void*)gk,
                    (__attribute__((address_space(3))) void*)(&Ks[buf][(w * 128 + i * 64) * 8]),
                    16, 0, 0);
            }
            {
                const int row = C >> 2, ch = C & 3;
                const ush* gv = vtbase + ((size_t)row << 11) + kt0 + ch * 8;
                __builtin_amdgcn_global_load_lds(
                    (const __attribute__((address_space(1))) void*)gv,
                    (__attribute__((address_space(3))) void*)(&Vs[buf][(w * 128 + i * 64) * 8]),
                    16, 0, 0);
            }
        }
    };

    float m = -1e30f, lsum = 0.f;
    f32x4 o[8] = {};

    stage(0, 0);
    __syncthreads();

    for (int ti = 0; ti < nt; ++ti) {
        const int cur = ti & 1;
        if (ti + 1 < nt) stage(ti + 1, cur ^ 1);
        const int kt0 = kstart + (ti << 5);
        const int qw0 = qb + 16 * w;
        const bool active = (kt0 + 31 >= qw0 - WINDOW_) && (kt0 <= qw0 + 15);
        if (active) {
            f32x4 st[2] = {};
#pragma unroll
            for (int s = 0; s < 2; ++s)
#pragma unroll
                for (int c = 0; c < 4; ++c) {
                    bf16x8 kf = *reinterpret_cast<const bf16x8*>(
                        &Ks[cur][(16 * s + t) * 128 + 32 * c + 8 * g]);
                    st[s] = __builtin_amdgcn_mfma_f32_16x16x32_bf16(kf, qf[c], st[s], 0, 0, 0);
                }
            const int tg = qb + 16 * w + t;
            float e[2][4];
            float mymax = -3e38f;
#pragma unroll
            for (int s = 0; s < 2; ++s)
#pragma unroll
                for (int r = 0; r < 4; ++r) {
                    const int key = kt0 + 16 * s + 4 * g + r;
                    const int dist = tg - key;
                    const bool valid = (dist >= 0) && (dist <= WINDOW_);
                    const float sv = valid ? st[s][r] : -3e38f;
                    e[s][r] = sv;
                    mymax = fmaxf(mymax, sv);
                }
            mymax = fmaxf(mymax, __shfl_xor(mymax, 16));
            mymax = fmaxf(mymax, __shfl_xor(mymax, 32));
            const float mn = fmaxf(m, mymax);
            const float sc = __expf(m - mn);
            float esum = 0.f;
#pragma unroll
            for (int s = 0; s < 2; ++s)
#pragma unroll
                for (int r = 0; r < 4; ++r) {
                    const float ev = __expf(e[s][r] - mn);
                    e[s][r] = ev;
                    esum += ev;
                }
            esum += __shfl_xor(esum, 16);
            esum += __shfl_xor(esum, 32);
            lsum = lsum * sc + esum;
            m = mn;
#pragma unroll
            for (int ds = 0; ds < 8; ++ds) {
                o[ds][0] *= sc; o[ds][1] *= sc; o[ds][2] *= sc; o[ds][3] *= sc;
            }
            uint32_t word[2][2];
#pragma unroll
            for (int s = 0; s < 2; ++s)
#pragma unroll
                for (int wd = 0; wd < 2; ++wd)
                    word[s][wd] = (uint32_t)f2bf(e[s][2 * wd])
                                | ((uint32_t)f2bf(e[s][2 * wd + 1]) << 16);
            u32x4 bw;
#pragma unroll
            for (int e2 = 0; e2 < 4; ++e2) {
                const int srcl = 16 * (2 * (g & 1) + (e2 >> 1)) + t;
                const uint32_t v0 = __shfl(word[0][e2 & 1], srcl);
                const uint32_t v1 = __shfl(word[1][e2 & 1], srcl);
                bw[e2] = (g >= 2) ? v1 : v0;
            }
            const bf16x8 pF = __builtin_bit_cast(bf16x8, bw);
#pragma unroll
            for (int ds = 0; ds < 8; ++ds) {
                bf16x8 vtF = *reinterpret_cast<const bf16x8*>(
                    &Vs[cur][(16 * ds + t) * 32 + 8 * g]);
                o[ds] = __builtin_amdgcn_mfma_f32_16x16x32_bf16(vtF, pF, o[ds], 0, 0, 0);
            }
        }
        __syncthreads();
    }

    const float linv = 1.0f / lsum;
    ush* cptr = ctx + (((size_t)b * T_ + qb + 16 * w + t) * (H_ * DH_)) + hh * DH_;
#pragma unroll
    for (int ds = 0; ds < 8; ++ds) {
        ushort4 pk;
        pk.x = f2bf(o[ds][0] * linv);
        pk.y = f2bf(o[ds][1] * linv);
        pk.z = f2bf(o[ds][2] * linv);
        pk.w = f2bf(o[ds][3] * linv);
        *reinterpret_cast<ushort4*>(cptr + 16 * ds + 4 * g) = pk;
    }
}

// ---------------- host launcher ----------------
extern "C" void kernel_launch(void* const* d_in, const int* in_sizes, int n_in,
                              void* d_out, int out_size, void* d_ws, size_t ws_size,
                              hipStream_t stream)
{
    const float* x   = (const float*)d_in[0];
    const float* wq  = (const float*)d_in[1];
    const float* wk  = (const float*)d_in[2];
    const float* wv  = (const float*)d_in[3];
    const float* wo  = (const float*)d_in[4];
    const float* qnw = (const float*)d_in[5];
    const float* knw = (const float*)d_in[6];
    float* out = (float*)d_out;

    ush* ws    = (ush*)d_ws;
    ush* xbf   = ws;                      // [4096][2048]
    ush* wqkv  = xbf  + 8388608;          // [4096][2048]
    ush* wobf  = wqkv + 8388608;          // [2048][2048]
    ush* qraw  = wobf + 4194304;          // [B][H][T][DH]
    ush* kraw  = qraw + 8388608;          // [B][HKV][T][DH]
    ush* vTb   = kraw + 4194304;          // [B][HKV][DH][T]
    ush* ctx   = vTb  + 4194304;          // [B][T][H*DH]

    cast_all<<<2048, 256, 0, stream>>>(x, wq, wk, wv, wo, ws);

    // QKV: 256x256 tiles -> 16x16 = 256 blocks (1/CU)
    gemm_bt5<8, 0><<<dim3(16, 16), 512, 0, stream>>>(xbf, wqkv, nullptr, qraw, kraw, vTb,
                                                     4096, 4096, 2048);
    norm_rope<<<(65536 + 32768) / 4, 256, 0, stream>>>(qraw, kraw, qnw, knw);
    attn_mfma<<<1024, 256, 0, stream>>>(qraw, kraw, vTb, ctx);
    // out-proj: 128x256 tiles -> 32x8 = 256 blocks (1/CU)
    gemm_bt5<4, 1><<<dim3(32, 8), 512, 0, stream>>>(ctx, wobf, out, nullptr, nullptr, nullptr,
                                                    4096, 2048, 2048);
    (void)in_sizes; (void)n_in; (void)out_size; (void)ws_size;
}